// Round 16
// baseline (147.796 us; speedup 1.0000x reference)
//
#include <hip/hip_runtime.h>

#define NB   512   // batch
#define IND  128   // input dim
#define H    512   // hidden
#define OUTD 25    // out dim

__device__ __forceinline__ float silu_f(float v) {
    return v / (1.0f + __expf(-v));
}

__device__ __forceinline__ float dot4(float4 a, float4 b) {
    return fmaf(a.x, b.x, fmaf(a.y, b.y, fmaf(a.z, b.z, a.w * b.w)));
}

// ---------------------------------------------------------------------------
// K1: hT[j][b] = silu(x[b] . Win[j] + bin[j])   (transposed output)
// grid (2, 256), 256 thr. lanes <-> batch b (coalesced hT writes).
// ---------------------------------------------------------------------------
__global__ __launch_bounds__(256) void k_hin(const float* __restrict__ x,
                                             const float* __restrict__ Win,
                                             const float* __restrict__ bin,
                                             float* __restrict__ hT) {
    const int b  = blockIdx.x * 256 + threadIdx.x;
    const int j0 = blockIdx.y * 2;

    const float4* xb = (const float4*)(x + (size_t)b * IND);     // per-lane
    const float4* w0 = (const float4*)(Win + (size_t)j0 * IND);  // blockIdx-uniform -> s_load
    const float4* w1 = (const float4*)(Win + (size_t)(j0 + 1) * IND);

    float a0 = 0.0f, a1 = 0.0f;
#pragma unroll 8
    for (int k4 = 0; k4 < IND / 4; ++k4) {
        const float4 xv = xb[k4];
        a0 += dot4(w0[k4], xv);
        a1 += dot4(w1[k4], xv);
    }
    hT[(size_t)j0 * NB + b]       = silu_f(a0 + bin[j0]);
    hT[(size_t)(j0 + 1) * NB + b] = silu_f(a1 + bin[j0 + 1]);
}

// ---------------------------------------------------------------------------
// K2: LDS-tiled double-buffered fp32 GEMM.
//   qkv[m][b][r] = silu( sum_k hT[k][b] * A_m[r][k] + B_m[r] )
// grid (8, 8, 3) = 192 blocks, 256 threads. Tile BM=64 (b) x BN=64 (r),
// BK=32, 16 K-steps, 4x4 micro-tile.
// ONE barrier per K-step: STORES writes buf^1 (disjoint from readers of
// buf), so only the store->compute edge needs sync. The barrier also
// guarantees all threads finished compute(cur) before cur is overwritten
// next iteration (each thread passes it only after its own compute+stores).
// ---------------------------------------------------------------------------
__global__ __launch_bounds__(256) void k_qkv(const float* __restrict__ hT,
                                             const float* __restrict__ Aq,
                                             const float* __restrict__ Bq,
                                             const float* __restrict__ Ak,
                                             const float* __restrict__ Bk,
                                             const float* __restrict__ Av,
                                             const float* __restrict__ Bv,
                                             float* __restrict__ qkv) {
    __shared__ float hs[2][32][64];    // 16 KB
    __shared__ float as_[2][32][68];   // 17.4 KB (pad 68: 16B rows, bank spread)

    const int t  = threadIdx.x;
    const int b0 = blockIdx.x * 64;
    const int r0 = blockIdx.y * 64;
    const int m  = blockIdx.z;

    const float* A  = (m == 0) ? Aq : (m == 1) ? Ak : Av;
    const float* Bm = (m == 0) ? Bq : (m == 1) ? Bk : Bv;

    const int kk_h = t >> 3, bq = t & 7;   // hT staging: row kk_h, b-quad bq (+0/+32)
    const int r_a  = t >> 2, qa = t & 3;   // A staging: row r_a, k-quad qa (+0/+4)
    const int tx   = t & 15, ty = t >> 4;  // compute: b-block tx*4, r-block ty*4

    float4 gh0, gh1, ga0, ga1;

#define LOADG(s) do {                                                          \
        const int k0_ = (s) * 32;                                              \
        gh0 = *(const float4*)(hT + (size_t)(k0_ + kk_h) * NB + b0 + bq * 4);  \
        gh1 = *(const float4*)(hT + (size_t)(k0_ + kk_h) * NB + b0 + 32 + bq * 4); \
        ga0 = *(const float4*)(A + (size_t)(r0 + r_a) * H + k0_ + qa * 4);     \
        ga1 = *(const float4*)(A + (size_t)(r0 + r_a) * H + k0_ + 16 + qa * 4);\
    } while (0)

#define STORES(buf) do {                                                       \
        *(float4*)(&hs[buf][kk_h][bq * 4])      = gh0;                         \
        *(float4*)(&hs[buf][kk_h][32 + bq * 4]) = gh1;                         \
        as_[buf][qa * 4 + 0][r_a] = ga0.x;                                     \
        as_[buf][qa * 4 + 1][r_a] = ga0.y;                                     \
        as_[buf][qa * 4 + 2][r_a] = ga0.z;                                     \
        as_[buf][qa * 4 + 3][r_a] = ga0.w;                                     \
        as_[buf][16 + qa * 4 + 0][r_a] = ga1.x;                                \
        as_[buf][16 + qa * 4 + 1][r_a] = ga1.y;                                \
        as_[buf][16 + qa * 4 + 2][r_a] = ga1.z;                                \
        as_[buf][16 + qa * 4 + 3][r_a] = ga1.w;                                \
    } while (0)

    float acc[4][4] = {};   // [i = r-offset][j = b-offset]

    LOADG(0);
    STORES(0);
    __syncthreads();

    int cur = 0;
    for (int s = 0; s < 16; ++s) {
        if (s < 15) LOADG(s + 1);      // next tile's loads fly during compute
#pragma unroll 8
        for (int kk = 0; kk < 32; ++kk) {
            const float4 hb = *(const float4*)(&hs[cur][kk][tx * 4]);
            const float4 ar = *(const float4*)(&as_[cur][kk][ty * 4]);
            acc[0][0] = fmaf(ar.x, hb.x, acc[0][0]);
            acc[0][1] = fmaf(ar.x, hb.y, acc[0][1]);
            acc[0][2] = fmaf(ar.x, hb.z, acc[0][2]);
            acc[0][3] = fmaf(ar.x, hb.w, acc[0][3]);
            acc[1][0] = fmaf(ar.y, hb.x, acc[1][0]);
            acc[1][1] = fmaf(ar.y, hb.y, acc[1][1]);
            acc[1][2] = fmaf(ar.y, hb.z, acc[1][2]);
            acc[1][3] = fmaf(ar.y, hb.w, acc[1][3]);
            acc[2][0] = fmaf(ar.z, hb.x, acc[2][0]);
            acc[2][1] = fmaf(ar.z, hb.y, acc[2][1]);
            acc[2][2] = fmaf(ar.z, hb.z, acc[2][2]);
            acc[2][3] = fmaf(ar.z, hb.w, acc[2][3]);
            acc[3][0] = fmaf(ar.w, hb.x, acc[3][0]);
            acc[3][1] = fmaf(ar.w, hb.y, acc[3][1]);
            acc[3][2] = fmaf(ar.w, hb.z, acc[3][2]);
            acc[3][3] = fmaf(ar.w, hb.w, acc[3][3]);
        }
        if (s < 15) {
            STORES(cur ^ 1);           // disjoint buffer: no race with readers
            __syncthreads();           // single barrier per K-step
            cur ^= 1;
        }
    }

    // epilogue: bias + silu, coalesced float4 stores along r
    const float4 bias = *(const float4*)(Bm + r0 + ty * 4);
#pragma unroll
    for (int j = 0; j < 4; ++j) {
        float4 o;
        o.x = silu_f(acc[0][j] + bias.x);
        o.y = silu_f(acc[1][j] + bias.y);
        o.z = silu_f(acc[2][j] + bias.z);
        o.w = silu_f(acc[3][j] + bias.w);
        *(float4*)(qkv + (size_t)m * NB * H + (size_t)(b0 + tx * 4 + j) * H + r0 + ty * 4) = o;
    }
#undef LOADG
#undef STORES
}

// ---------------------------------------------------------------------------
// K3 (fused attn + out): per batch row b:
//   ctx[i] = silu( sum_j softmax_j(Q[i]*K[j]) * V[j] )   (exact row-max via
//   s*maxK / s*minK -- rounding is monotone, matches reference exactly)
//   y = silu(ctx @ Wout^T + bout);  out[b] = q^T M q + mpp
// exp(s*k - m) computed as exp2(fmaf(s*L2E, k, -m*L2E)): v_exp_f32 IS exp2,
// so folding log2e into the fma constants deletes the per-exp v_mul.
// ---------------------------------------------------------------------------
__global__ __launch_bounds__(512) void k_attn_out(const float* __restrict__ qkv,
                                                  const float* __restrict__ Wout,
                                                  const float* __restrict__ bout,
                                                  float* __restrict__ out) {
    __shared__ float wmx[8], wmn[8];
    __shared__ float cs[H];
    __shared__ float part[OUTD][8];
    __shared__ float yrow[OUTD];

    const int b = blockIdx.x;
    const int t = threadIdx.x;

    const float* Q = qkv + (size_t)b * H;
    const float* K = qkv + 1 * (size_t)NB * H + (size_t)b * H;
    const float* V = qkv + 2 * (size_t)NB * H + (size_t)b * H;

    // --- global max/min of K row ---
    const float kv = K[t];
    float mx = kv, mn = kv;
#pragma unroll
    for (int o = 32; o > 0; o >>= 1) {
        mx = fmaxf(mx, __shfl_xor(mx, o, 64));
        mn = fminf(mn, __shfl_xor(mn, o, 64));
    }
    const int lane = t & 63, w = t >> 6;
    if (lane == 0) { wmx[w] = mx; wmn[w] = mn; }
    __syncthreads();

    float gmx = wmx[0], gmn = wmn[0];
#pragma unroll
    for (int i = 1; i < 8; ++i) {
        gmx = fmaxf(gmx, wmx[i]);
        gmn = fminf(gmn, wmn[i]);
    }

    // --- softmax-weighted V accumulation (exp2-folded) ---
    const float L2E = 1.44269504088896341f;
    const float s   = Q[t];
    const float m   = (s >= 0.0f) ? s * gmx : s * gmn;
    const float s2  = s * L2E;
    const float nm2 = -m * L2E;

    float den = 0.0f, num = 0.0f;
    const float4* K4p = (const float4*)K;
    const float4* V4p = (const float4*)V;
#pragma unroll 4
    for (int j4 = 0; j4 < H / 4; ++j4) {
        const float4 kj = K4p[j4];
        const float4 vj = V4p[j4];
        const float e0 = exp2f(fmaf(s2, kj.x, nm2));
        const float e1 = exp2f(fmaf(s2, kj.y, nm2));
        const float e2 = exp2f(fmaf(s2, kj.z, nm2));
        const float e3 = exp2f(fmaf(s2, kj.w, nm2));
        den += (e0 + e1) + (e2 + e3);
        num = fmaf(e0, vj.x, num);
        num = fmaf(e1, vj.y, num);
        num = fmaf(e2, vj.z, num);
        num = fmaf(e3, vj.w, num);
    }
    cs[t] = silu_f(num / den);
    __syncthreads();

    // --- y = silu(cs @ Wout^T + bout), 25 outputs x 8 K-partials ---
    if (t < OUTD * 8) {
        const int o = t >> 3, p = t & 7;
        const float4* wv = (const float4*)(Wout + (size_t)o * H + p * 64);
        const float4* c  = (const float4*)(cs + p * 64);
        float a = 0.0f;
#pragma unroll
        for (int k = 0; k < 16; ++k) a += dot4(wv[k], c[k]);
        part[o][p] = a;
    }
    __syncthreads();

    if (t < OUTD) {
        float a = bout[t];
#pragma unroll
        for (int p = 0; p < 8; ++p) a += part[t][p];
        yrow[t] = silu_f(a);
    }
    __syncthreads();

    // --- quadratic form ---
    if (t == 0) {
        float ms[5];
#pragma unroll
        for (int g = 0; g < 5; ++g) {
            float a = 0.0f;
#pragma unroll
            for (int k = 0; k < 5; ++k) {
                const float yv = yrow[g * 5 + k];
                a = fmaf(yv, yv, a);
            }
            ms[g] = a;
        }
        const float m11 = ms[0], m12 = ms[1], m21 = ms[2], m22 = ms[3], mpp = ms[4];
        const float q0 = yrow[0], q1 = yrow[1], q2 = yrow[2], q3 = yrow[3];
        const float quad = m11 * (q0 * q0 + q1 * q1)
                         + (m12 + m21) * (q0 * q2 + q1 * q3)
                         + m22 * (q2 * q2 + q3 * q3);
        out[b] = quad + mpp;
    }
}

// ---------------------------------------------------------------------------
extern "C" void kernel_launch(void* const* d_in, const int* in_sizes, int n_in,
                              void* d_out, int out_size, void* d_ws, size_t ws_size,
                              hipStream_t stream) {
    const float* x    = (const float*)d_in[0];
    // d_in[1] = na (int32, unused by the reference math)
    const float* Win  = (const float*)d_in[2];
    const float* bin  = (const float*)d_in[3];
    const float* Aq   = (const float*)d_in[4];
    const float* Bq   = (const float*)d_in[5];
    const float* Ak   = (const float*)d_in[6];
    const float* Bk   = (const float*)d_in[7];
    const float* Av   = (const float*)d_in[8];
    const float* Bv   = (const float*)d_in[9];
    const float* Wout = (const float*)d_in[10];
    const float* bout = (const float*)d_in[11];

    float* out = (float*)d_out;
    float* ws  = (float*)d_ws;

    float* hT  = ws;                          // 512*512   (hT[k][b])
    float* qkv = ws + (size_t)NB * H;         // 3 * 512*512  (qkv[m][b][r])

    k_hin     <<<dim3(2, 256),  dim3(256), 0, stream>>>(x, Win, bin, hT);
    k_qkv     <<<dim3(8, 8, 3), dim3(256), 0, stream>>>(hT, Aq, Bq, Ak, Bk, Av, Bv, qkv);
    k_attn_out<<<dim3(NB),      dim3(512), 0, stream>>>(qkv, Wout, bout, out);
}

// Round 17
// 132.702 us; speedup vs baseline: 1.1137x; 1.1137x over previous
//
#include <hip/hip_runtime.h>

#define NB   512   // batch
#define IND  128   // input dim
#define H    512   // hidden
#define OUTD 25    // out dim

__device__ __forceinline__ float silu_f(float v) {
    return v / (1.0f + __expf(-v));
}

__device__ __forceinline__ float dot4(float4 a, float4 b) {
    return fmaf(a.x, b.x, fmaf(a.y, b.y, fmaf(a.z, b.z, a.w * b.w)));
}

// ---------------------------------------------------------------------------
// K1: hT[j][b] = silu(x[b] . Win[j] + bin[j])   (transposed output)
// grid (2, 256), 256 thr. lanes <-> batch b (coalesced hT writes).
// ---------------------------------------------------------------------------
__global__ __launch_bounds__(256) void k_hin(const float* __restrict__ x,
                                             const float* __restrict__ Win,
                                             const float* __restrict__ bin,
                                             float* __restrict__ hT) {
    const int b  = blockIdx.x * 256 + threadIdx.x;
    const int j0 = blockIdx.y * 2;

    const float4* xb = (const float4*)(x + (size_t)b * IND);     // per-lane
    const float4* w0 = (const float4*)(Win + (size_t)j0 * IND);  // blockIdx-uniform -> s_load
    const float4* w1 = (const float4*)(Win + (size_t)(j0 + 1) * IND);

    float a0 = 0.0f, a1 = 0.0f;
#pragma unroll 8
    for (int k4 = 0; k4 < IND / 4; ++k4) {
        const float4 xv = xb[k4];
        a0 += dot4(w0[k4], xv);
        a1 += dot4(w1[k4], xv);
    }
    hT[(size_t)j0 * NB + b]       = silu_f(a0 + bin[j0]);
    hT[(size_t)(j0 + 1) * NB + b] = silu_f(a1 + bin[j0 + 1]);
}

// ---------------------------------------------------------------------------
// K2: LDS-tiled double-buffered fp32 GEMM.
//   qkv[m][b][r] = silu( sum_k hT[k][b] * A_m[r][k] + B_m[r] )
// grid (8, 8, 3) = 192 blocks, 256 threads. Tile BM=64 (b) x BN=64 (r),
// BK=32, 16 K-steps, 4x4 micro-tile. ONE barrier per K-step (disjoint
// double buffers).
// ---------------------------------------------------------------------------
__global__ __launch_bounds__(256) void k_qkv(const float* __restrict__ hT,
                                             const float* __restrict__ Aq,
                                             const float* __restrict__ Bq,
                                             const float* __restrict__ Ak,
                                             const float* __restrict__ Bk,
                                             const float* __restrict__ Av,
                                             const float* __restrict__ Bv,
                                             float* __restrict__ qkv) {
    __shared__ float hs[2][32][64];    // 16 KB
    __shared__ float as_[2][32][68];   // 17.4 KB (pad 68: 16B rows, bank spread)

    const int t  = threadIdx.x;
    const int b0 = blockIdx.x * 64;
    const int r0 = blockIdx.y * 64;
    const int m  = blockIdx.z;

    const float* A  = (m == 0) ? Aq : (m == 1) ? Ak : Av;
    const float* Bm = (m == 0) ? Bq : (m == 1) ? Bk : Bv;

    const int kk_h = t >> 3, bq = t & 7;   // hT staging: row kk_h, b-quad bq (+0/+32)
    const int r_a  = t >> 2, qa = t & 3;   // A staging: row r_a, k-quad qa (+0/+4)
    const int tx   = t & 15, ty = t >> 4;  // compute: b-block tx*4, r-block ty*4

    float4 gh0, gh1, ga0, ga1;

#define LOADG(s) do {                                                          \
        const int k0_ = (s) * 32;                                              \
        gh0 = *(const float4*)(hT + (size_t)(k0_ + kk_h) * NB + b0 + bq * 4);  \
        gh1 = *(const float4*)(hT + (size_t)(k0_ + kk_h) * NB + b0 + 32 + bq * 4); \
        ga0 = *(const float4*)(A + (size_t)(r0 + r_a) * H + k0_ + qa * 4);     \
        ga1 = *(const float4*)(A + (size_t)(r0 + r_a) * H + k0_ + 16 + qa * 4);\
    } while (0)

#define STORES(buf) do {                                                       \
        *(float4*)(&hs[buf][kk_h][bq * 4])      = gh0;                         \
        *(float4*)(&hs[buf][kk_h][32 + bq * 4]) = gh1;                         \
        as_[buf][qa * 4 + 0][r_a] = ga0.x;                                     \
        as_[buf][qa * 4 + 1][r_a] = ga0.y;                                     \
        as_[buf][qa * 4 + 2][r_a] = ga0.z;                                     \
        as_[buf][qa * 4 + 3][r_a] = ga0.w;                                     \
        as_[buf][16 + qa * 4 + 0][r_a] = ga1.x;                                \
        as_[buf][16 + qa * 4 + 1][r_a] = ga1.y;                                \
        as_[buf][16 + qa * 4 + 2][r_a] = ga1.z;                                \
        as_[buf][16 + qa * 4 + 3][r_a] = ga1.w;                                \
    } while (0)

    float acc[4][4] = {};   // [i = r-offset][j = b-offset]

    LOADG(0);
    STORES(0);
    __syncthreads();

    int cur = 0;
    for (int s = 0; s < 16; ++s) {
        if (s < 15) LOADG(s + 1);      // next tile's loads fly during compute
#pragma unroll 8
        for (int kk = 0; kk < 32; ++kk) {
            const float4 hb = *(const float4*)(&hs[cur][kk][tx * 4]);
            const float4 ar = *(const float4*)(&as_[cur][kk][ty * 4]);
            acc[0][0] = fmaf(ar.x, hb.x, acc[0][0]);
            acc[0][1] = fmaf(ar.x, hb.y, acc[0][1]);
            acc[0][2] = fmaf(ar.x, hb.z, acc[0][2]);
            acc[0][3] = fmaf(ar.x, hb.w, acc[0][3]);
            acc[1][0] = fmaf(ar.y, hb.x, acc[1][0]);
            acc[1][1] = fmaf(ar.y, hb.y, acc[1][1]);
            acc[1][2] = fmaf(ar.y, hb.z, acc[1][2]);
            acc[1][3] = fmaf(ar.y, hb.w, acc[1][3]);
            acc[2][0] = fmaf(ar.z, hb.x, acc[2][0]);
            acc[2][1] = fmaf(ar.z, hb.y, acc[2][1]);
            acc[2][2] = fmaf(ar.z, hb.z, acc[2][2]);
            acc[2][3] = fmaf(ar.z, hb.w, acc[2][3]);
            acc[3][0] = fmaf(ar.w, hb.x, acc[3][0]);
            acc[3][1] = fmaf(ar.w, hb.y, acc[3][1]);
            acc[3][2] = fmaf(ar.w, hb.z, acc[3][2]);
            acc[3][3] = fmaf(ar.w, hb.w, acc[3][3]);
        }
        if (s < 15) {
            STORES(cur ^ 1);           // disjoint buffer: no race with readers
            __syncthreads();           // single barrier per K-step
            cur ^= 1;
        }
    }

    // epilogue: bias + silu, coalesced float4 stores along r
    const float4 bias = *(const float4*)(Bm + r0 + ty * 4);
#pragma unroll
    for (int j = 0; j < 4; ++j) {
        float4 o;
        o.x = silu_f(acc[0][j] + bias.x);
        o.y = silu_f(acc[1][j] + bias.y);
        o.z = silu_f(acc[2][j] + bias.z);
        o.w = silu_f(acc[3][j] + bias.w);
        *(float4*)(qkv + (size_t)m * NB * H + (size_t)(b0 + tx * 4 + j) * H + r0 + ty * 4) = o;
    }
#undef LOADG
#undef STORES
}

// ---------------------------------------------------------------------------
// K3 (fused attn + out): per batch row b:
//   ctx[i] = silu( sum_j softmax_j(Q[i]*K[j]) * V[j] )   (exact row-max via
//   s*maxK / s*minK -- rounding is monotone, matches reference exactly)
//   y = silu(ctx @ Wout^T + bout);  out[b] = q^T M q + mpp
// exp via __builtin_amdgcn_exp2f = bare v_exp_f32 (v_exp IS exp2): no OCML
// denormal fixup (exp2f regression, r16 postmortem) and no per-exp v_mul
// (log2e folded into the fma constants).
// ---------------------------------------------------------------------------
__global__ __launch_bounds__(512) void k_attn_out(const float* __restrict__ qkv,
                                                  const float* __restrict__ Wout,
                                                  const float* __restrict__ bout,
                                                  float* __restrict__ out) {
    __shared__ float wmx[8], wmn[8];
    __shared__ float cs[H];
    __shared__ float part[OUTD][8];
    __shared__ float yrow[OUTD];

    const int b = blockIdx.x;
    const int t = threadIdx.x;

    const float* Q = qkv + (size_t)b * H;
    const float* K = qkv + 1 * (size_t)NB * H + (size_t)b * H;
    const float* V = qkv + 2 * (size_t)NB * H + (size_t)b * H;

    // --- global max/min of K row ---
    const float kv = K[t];
    float mx = kv, mn = kv;
#pragma unroll
    for (int o = 32; o > 0; o >>= 1) {
        mx = fmaxf(mx, __shfl_xor(mx, o, 64));
        mn = fminf(mn, __shfl_xor(mn, o, 64));
    }
    const int lane = t & 63, w = t >> 6;
    if (lane == 0) { wmx[w] = mx; wmn[w] = mn; }
    __syncthreads();

    float gmx = wmx[0], gmn = wmn[0];
#pragma unroll
    for (int i = 1; i < 8; ++i) {
        gmx = fmaxf(gmx, wmx[i]);
        gmn = fminf(gmn, wmn[i]);
    }

    // --- softmax-weighted V accumulation (bare v_exp_f32, exp2-folded) ---
    const float L2E = 1.44269504088896341f;
    const float s   = Q[t];
    const float m   = (s >= 0.0f) ? s * gmx : s * gmn;
    const float s2  = s * L2E;
    const float nm2 = -m * L2E;

    float den = 0.0f, num = 0.0f;
    const float4* K4p = (const float4*)K;
    const float4* V4p = (const float4*)V;
#pragma unroll 4
    for (int j4 = 0; j4 < H / 4; ++j4) {
        const float4 kj = K4p[j4];
        const float4 vj = V4p[j4];
        const float e0 = __builtin_amdgcn_exp2f(fmaf(s2, kj.x, nm2));
        const float e1 = __builtin_amdgcn_exp2f(fmaf(s2, kj.y, nm2));
        const float e2 = __builtin_amdgcn_exp2f(fmaf(s2, kj.z, nm2));
        const float e3 = __builtin_amdgcn_exp2f(fmaf(s2, kj.w, nm2));
        den += (e0 + e1) + (e2 + e3);
        num = fmaf(e0, vj.x, num);
        num = fmaf(e1, vj.y, num);
        num = fmaf(e2, vj.z, num);
        num = fmaf(e3, vj.w, num);
    }
    cs[t] = silu_f(num / den);
    __syncthreads();

    // --- y = silu(cs @ Wout^T + bout), 25 outputs x 8 K-partials ---
    // k-order rotated per p: un-rotated, all 8 p-groups hit bank (k*4)%32
    // simultaneously (8-way conflict, 739K cycles in r16 profile); rotation
    // spreads them over 4 bank offsets (<=2-way, free). Sum order only.
    if (t < OUTD * 8) {
        const int o = t >> 3, p = t & 7;
        const float4* wv = (const float4*)(Wout + (size_t)o * H + p * 64);
        const float4* c  = (const float4*)(cs + p * 64);
        float a = 0.0f;
#pragma unroll
        for (int kk = 0; kk < 16; ++kk) {
            const int k = (kk + p * 2) & 15;
            a += dot4(wv[k], c[k]);
        }
        part[o][p] = a;
    }
    __syncthreads();

    if (t < OUTD) {
        float a = bout[t];
#pragma unroll
        for (int p = 0; p < 8; ++p) a += part[t][p];
        yrow[t] = silu_f(a);
    }
    __syncthreads();

    // --- quadratic form ---
    if (t == 0) {
        float ms[5];
#pragma unroll
        for (int g = 0; g < 5; ++g) {
            float a = 0.0f;
#pragma unroll
            for (int k = 0; k < 5; ++k) {
                const float yv = yrow[g * 5 + k];
                a = fmaf(yv, yv, a);
            }
            ms[g] = a;
        }
        const float m11 = ms[0], m12 = ms[1], m21 = ms[2], m22 = ms[3], mpp = ms[4];
        const float q0 = yrow[0], q1 = yrow[1], q2 = yrow[2], q3 = yrow[3];
        const float quad = m11 * (q0 * q0 + q1 * q1)
                         + (m12 + m21) * (q0 * q2 + q1 * q3)
                         + m22 * (q2 * q2 + q3 * q3);
        out[b] = quad + mpp;
    }
}

// ---------------------------------------------------------------------------
extern "C" void kernel_launch(void* const* d_in, const int* in_sizes, int n_in,
                              void* d_out, int out_size, void* d_ws, size_t ws_size,
                              hipStream_t stream) {
    const float* x    = (const float*)d_in[0];
    // d_in[1] = na (int32, unused by the reference math)
    const float* Win  = (const float*)d_in[2];
    const float* bin  = (const float*)d_in[3];
    const float* Aq   = (const float*)d_in[4];
    const float* Bq   = (const float*)d_in[5];
    const float* Ak   = (const float*)d_in[6];
    const float* Bk   = (const float*)d_in[7];
    const float* Av   = (const float*)d_in[8];
    const float* Bv   = (const float*)d_in[9];
    const float* Wout = (const float*)d_in[10];
    const float* bout = (const float*)d_in[11];

    float* out = (float*)d_out;
    float* ws  = (float*)d_ws;

    float* hT  = ws;                          // 512*512   (hT[k][b])
    float* qkv = ws + (size_t)NB * H;         // 3 * 512*512  (qkv[m][b][r])

    k_hin     <<<dim3(2, 256),  dim3(256), 0, stream>>>(x, Win, bin, hT);
    k_qkv     <<<dim3(8, 8, 3), dim3(256), 0, stream>>>(hT, Aq, Bq, Ak, Bk, Av, Bv, qkv);
    k_attn_out<<<dim3(NB),      dim3(512), 0, stream>>>(qkv, Wout, bout, out);
}